// Round 6
// baseline (961.615 us; speedup 1.0000x reference)
//
#include <hip/hip_runtime.h>
#include <hip/hip_bf16.h>
#include <math.h>

// ---------------- workspace layout (bytes) ----------------
#define OFF_P0 0
#define OFF_P1 16777216
#define OFF_P2 33554432
#define OFF_DS 37748736
#define OFF_IT 38273024
#define OFF_ST 39059456
#define OFF_AC 39063552

// ---------------- conv 3x3 SAME + bias + relu (v5) ----------------
// Tile 32x16 px, 256 threads: each thread 2 horizontal px x 8 oc (acc[16]).
// Input staged in LDS CB cin at a time (18x36-padded rows, 10.4 KB single
// buffer). Per cc: 6 aligned ds_read_b64 feed 144 FMA (24:1). Weights via
// block-uniform s_load. Grid: conv1/2 = 1024 blocks, conv3/4 = 512.
template<int CB>
__global__ __launch_bounds__(256) void conv3x3_v5(
    const float* __restrict__ in, const float* __restrict__ w,
    const float* __restrict__ b, float* __restrict__ out,
    int N, int Cin, int Cout, int H, int W)
{
    const int TW = W >> 5, TH = H >> 4, OCG = Cout >> 3;
    int bid = blockIdx.x;
    int txt = bid % TW; bid /= TW;
    int tyt = bid % TH; bid /= TH;
    int ocg = bid % OCG; bid /= OCG;
    int n = bid;
    int x0 = txt * 32, y0 = tyt * 16;
    int tid = threadIdx.x;
    int tx2 = (tid & 15) * 2, ty = tid >> 4;

    __shared__ float lin[CB][18][36];

    float acc[8][2];
#pragma unroll
    for (int oc = 0; oc < 8; ++oc) { acc[oc][0] = 0.f; acc[oc][1] = 0.f; }

    const float* in_n = in + (size_t)n * Cin * H * W;
    const float* w_g  = w + (size_t)(ocg * 8) * Cin * 9;

    for (int c0 = 0; c0 < Cin; c0 += CB) {
        __syncthreads();
        // stage CB x 18 x 34 input tile (zero-padded halo), rows padded to 36
        for (int i = tid; i < CB * 612; i += 256) {
            int cc = i / 612;
            int rem = i - cc * 612;
            int r = rem / 34;
            int c = rem - r * 34;
            int y = y0 - 1 + r, x = x0 - 1 + c;
            float v = 0.f;
            if ((unsigned)y < (unsigned)H && (unsigned)x < (unsigned)W)
                v = in_n[(size_t)(c0 + cc) * H * W + y * W + x];
            lin[cc][r][c] = v;
        }
        __syncthreads();

#pragma unroll
        for (int cc = 0; cc < CB; ++cc) {
            float p[3][4];
#pragma unroll
            for (int r = 0; r < 3; ++r) {
                const float* row = &lin[cc][ty + r][tx2];
                float2 a  = *(const float2*)row;
                float2 b2 = *(const float2*)(row + 2);
                p[r][0] = a.x; p[r][1] = a.y; p[r][2] = b2.x; p[r][3] = b2.y;
            }
            const float* wp = w_g + (size_t)(c0 + cc) * 9;
#pragma unroll
            for (int oc = 0; oc < 8; ++oc) {
                const float* wq = wp + (size_t)oc * Cin * 9;  // block-uniform -> s_load
                float a0 = acc[oc][0], a1 = acc[oc][1];
#pragma unroll
                for (int jr = 0; jr < 3; ++jr) {
                    float w0 = wq[jr * 3 + 0];
                    float w1 = wq[jr * 3 + 1];
                    float w2 = wq[jr * 3 + 2];
                    a0 = fmaf(w0, p[jr][0], a0);
                    a1 = fmaf(w0, p[jr][1], a1);
                    a0 = fmaf(w1, p[jr][1], a0);
                    a1 = fmaf(w1, p[jr][2], a1);
                    a0 = fmaf(w2, p[jr][2], a0);
                    a1 = fmaf(w2, p[jr][3], a1);
                }
                acc[oc][0] = a0; acc[oc][1] = a1;
            }
        }
    }

#pragma unroll
    for (int oc = 0; oc < 8; ++oc) {
        float bias = b[ocg * 8 + oc];
        float2 v;
        v.x = fmaxf(acc[oc][0] + bias, 0.f);
        v.y = fmaxf(acc[oc][1] + bias, 0.f);
        *(float2*)&out[((size_t)(n * Cout + ocg * 8 + oc) * H + (y0 + ty)) * W + (x0 + tx2)] = v;
    }
}

// ---------------- 2x2 pools ----------------
__global__ __launch_bounds__(256) void maxpool2_k(const float* __restrict__ in,
                                                  float* __restrict__ out, int total)
{
    int tid = blockIdx.x * 256 + threadIdx.x;
    if (tid >= total) return;
    int wo = tid & 63, ho = (tid >> 6) & 63, ch = tid >> 12;
    const float* p = in + (size_t)ch * 16384 + (size_t)(ho * 2) * 128 + wo * 2;
    out[tid] = fmaxf(fmaxf(p[0], p[1]), fmaxf(p[128], p[129]));
}

__global__ __launch_bounds__(256) void avgpool2_k(const float* __restrict__ in,
                                                  float* __restrict__ out, int total)
{
    int tid = blockIdx.x * 256 + threadIdx.x;
    if (tid >= total) return;
    int wo = tid & 63, ho = (tid >> 6) & 63, ch = tid >> 12;
    const float* p = in + (size_t)ch * 16384 + (size_t)(ho * 2) * 128 + wo * 2;
    out[tid] = 0.25f * ((p[0] + p[1]) + (p[128] + p[129]));
}

// ---------------- batchnorm stats ----------------
__global__ __launch_bounds__(256) void bn_stats_k(const float* __restrict__ x,
                                                  float* __restrict__ stats,
                                                  int C, int HW, int N)
{
    int c = blockIdx.x, tid = threadIdx.x;
    int M = N * HW;
    double s = 0.0, s2 = 0.0;
    for (int i = tid; i < M; i += 256) {
        int n = i / HW, r = i - n * HW;
        float v = x[((size_t)(n * C + c)) * HW + r];
        s += v;
        s2 += (double)v * (double)v;
    }
    __shared__ double ls[256], ls2[256];
    ls[tid] = s; ls2[tid] = s2;
    __syncthreads();
    for (int st = 128; st > 0; st >>= 1) {
        if (tid < st) { ls[tid] += ls[tid + st]; ls2[tid] += ls2[tid + st]; }
        __syncthreads();
    }
    if (tid == 0) {
        double mean = ls[0] / M;
        double var = ls2[0] / M - mean * mean;
        stats[c] = (float)mean;
        stats[C + c] = (float)(1.0 / sqrt(var + 1e-5));
    }
}

// ---------------- normalize + transpose fich: (4,128,64,64)->(4,64,64,128) ---
__global__ __launch_bounds__(256) void norm_transpose_f_k(
    const float* __restrict__ x, const float* __restrict__ stats,
    float* __restrict__ xt)
{
    int bid = blockIdx.x;           // n(4) x h(64) x ct(4) x wt(2)
    int wt = bid & 1; bid >>= 1;
    int ct = bid & 3; bid >>= 2;
    int h = bid & 63; bid >>= 6;
    int n = bid;
    int tx = threadIdx.x & 31, ty = threadIdx.x >> 5;
    __shared__ float lds[32][33];
    int c0 = ct * 32, w0 = wt * 32;
#pragma unroll
    for (int i = 0; i < 4; ++i) {
        int c = c0 + ty + i * 8;
        float v = x[(((size_t)n * 128 + c) * 64 + h) * 64 + (w0 + tx)];
        lds[ty + i * 8][tx] = (v - stats[c]) * stats[128 + c];
    }
    __syncthreads();
#pragma unroll
    for (int i = 0; i < 4; ++i) {
        int wcol = w0 + ty + i * 8;
        xt[(((size_t)(n * 64) + h) * 64 + wcol) * 128 + c0 + tx] = lds[tx][ty + i * 8];
    }
}

// ---------------- normalize + transpose images ----------------
__global__ __launch_bounds__(256) void norm_transpose_i_k(
    const float* __restrict__ x, const float* __restrict__ stats,
    float* __restrict__ it)
{
    int tid = blockIdx.x * 256 + threadIdx.x;   // 65536
    int n = tid >> 14;
    int hw = tid & 16383;
#pragma unroll
    for (int c = 0; c < 3; ++c) {
        float v = x[(((size_t)n * 3 + c) << 14) + hw];
        it[(size_t)tid * 3 + c] = (v - stats[c]) * stats[3 + c];
    }
}

__global__ void zero_k(float* acc)
{
    if (threadIdx.x < 128) acc[threadIdx.x] = 0.f;
}

// ---------------- modularity on VGG features (v2) ----------------
__global__ __launch_bounds__(64) void modularity64_v2(
    const float* __restrict__ xt,   // (4,64,64,128)
    const float* __restrict__ seg,  // (4,8,64,64)
    float* __restrict__ acc)        // [0..31] num, [32..63] den
{
    __shared__ float fl[12][12][20];   // 16 used + 4 pad
    __shared__ float sl[8][12][14];    // 12 used + 2 pad

    int t = threadIdx.x;
    int tx = t & 7, ty = t >> 3;
    int bid = blockIdx.x;              // n(4) x by(8) x bx(8)
    int bx = bid & 7; bid >>= 3;
    int by = bid & 7; bid >>= 3;
    int n = bid;
    int x0 = bx * 8, y0 = by * 8;

    for (int i = t; i < 8 * 144; i += 64) {
        int k = i / 144;
        int rem = i - k * 144;
        int r = rem / 12, c = rem - r * 12;
        int y = y0 - 2 + r, x = x0 - 2 + c;
        float v = 0.f;
        if ((unsigned)y < 64u && (unsigned)x < 64u)
            v = seg[((size_t)(n * 8 + k) * 64 + y) * 64 + x];
        sl[k][r][c] = v;
    }

    float d2p[25];
#pragma unroll
    for (int di = 0; di < 5; ++di)
#pragma unroll
        for (int dj = 0; dj < 5; ++dj) {
            int y2 = y0 + ty + di - 2, x2 = x0 + tx + dj - 2;
            d2p[di * 5 + dj] = ((unsigned)y2 < 64u && (unsigned)x2 < 64u) ? 0.f : 1e30f;
        }

    for (int ch0 = 0; ch0 < 128; ch0 += 16) {
        __syncthreads();
        for (int i = t; i < 576; i += 64) {
            int pix = i >> 2, q = i & 3;
            int r = pix / 12, c = pix - r * 12;
            int y = y0 - 2 + r, x = x0 - 2 + c;
            float4 v = make_float4(0.f, 0.f, 0.f, 0.f);
            if ((unsigned)y < 64u && (unsigned)x < 64u)
                v = *(const float4*)&xt[((size_t)((n * 64 + y) * 64 + x)) * 128 + ch0 + q * 4];
            *(float4*)&fl[r][c][q * 4] = v;
        }
        __syncthreads();

        float4 c0 = *(const float4*)&fl[ty + 2][tx + 2][0];
        float4 c1 = *(const float4*)&fl[ty + 2][tx + 2][4];
        float4 c2 = *(const float4*)&fl[ty + 2][tx + 2][8];
        float4 c3 = *(const float4*)&fl[ty + 2][tx + 2][12];
#pragma unroll
        for (int di = 0; di < 5; ++di)
#pragma unroll
            for (int dj = 0; dj < 5; ++dj) {
                const float* np = &fl[ty + di][tx + dj][0];
                float4 v0 = *(const float4*)(np + 0);
                float4 v1 = *(const float4*)(np + 4);
                float4 v2 = *(const float4*)(np + 8);
                float4 v3 = *(const float4*)(np + 12);
                float d = d2p[di * 5 + dj];
                float e;
                e = c0.x - v0.x; d = fmaf(e, e, d);
                e = c0.y - v0.y; d = fmaf(e, e, d);
                e = c0.z - v0.z; d = fmaf(e, e, d);
                e = c0.w - v0.w; d = fmaf(e, e, d);
                e = c1.x - v1.x; d = fmaf(e, e, d);
                e = c1.y - v1.y; d = fmaf(e, e, d);
                e = c1.z - v1.z; d = fmaf(e, e, d);
                e = c1.w - v1.w; d = fmaf(e, e, d);
                e = c2.x - v2.x; d = fmaf(e, e, d);
                e = c2.y - v2.y; d = fmaf(e, e, d);
                e = c2.z - v2.z; d = fmaf(e, e, d);
                e = c2.w - v2.w; d = fmaf(e, e, d);
                e = c3.x - v3.x; d = fmaf(e, e, d);
                e = c3.y - v3.y; d = fmaf(e, e, d);
                e = c3.z - v3.z; d = fmaf(e, e, d);
                e = c3.w - v3.w; d = fmaf(e, e, d);
                d2p[di * 5 + dj] = d;
            }
    }

    const float minus_inv2s2 = -1.0f / (2.0f * 0.02f * 0.02f); // -1250
    float wgt[25];
    float w1 = 0.f;
#pragma unroll
    for (int j = 0; j < 25; ++j) {
        wgt[j] = expf(d2p[j] * minus_inv2s2);
        w1 += wgt[j];
    }

#pragma unroll
    for (int k = 0; k < 8; ++k) {
        float s = 0.f;
#pragma unroll
        for (int di = 0; di < 5; ++di)
#pragma unroll
            for (int dj = 0; dj < 5; ++dj)
                s = fmaf(wgt[di * 5 + dj], sl[k][ty + di][tx + dj], s);
        float sc = sl[k][ty + 2][tx + 2];
        float numk = s * sc;
        float denk = w1 * sc;
#pragma unroll
        for (int sft = 32; sft > 0; sft >>= 1) {
            numk += __shfl_xor(numk, sft, 64);
            denk += __shfl_xor(denk, sft, 64);
        }
        if (t == 0) {
            atomicAdd(&acc[n * 8 + k], numk);
            atomicAdd(&acc[32 + n * 8 + k], denk);
        }
    }
}

// ---------------- modularity on images ----------------
__global__ __launch_bounds__(256) void modularity128_k(
    const float* __restrict__ it,   // (4,128,128,3)
    const float* __restrict__ seg,  // (4,8,128,128)
    float* __restrict__ acc)
{
    const float inv2s2 = 1.0f / (2.0f * 0.2f * 0.2f);
    int tid = blockIdx.x * 256 + threadIdx.x;
    int lane = threadIdx.x & 63;
    int w = tid & 127;
    int h = (tid >> 7) & 127;
    int n = tid >> 14;

    const float* cp = it + (size_t)tid * 3;
    float c0 = cp[0], c1 = cp[1], c2 = cp[2];
    float segc[8], num[8];
#pragma unroll
    for (int k = 0; k < 8; ++k) {
        segc[k] = seg[((size_t)(n * 8 + k) * 128 + h) * 128 + w];
        num[k] = 0.f;
    }
    float w1 = 0.f;

    for (int di = -2; di <= 2; ++di) {
        int h2 = h + di;
        if (h2 < 0 || h2 >= 128) continue;
        for (int dj = -2; dj <= 2; ++dj) {
            int w2 = w + dj;
            if (w2 < 0 || w2 >= 128) continue;
            const float* vp = it + ((size_t)((n * 128 + h2) * 128 + w2)) * 3;
            float d0 = c0 - vp[0], d1 = c1 - vp[1], d2v = c2 - vp[2];
            float d2 = fmaf(d2v, d2v, fmaf(d1, d1, d0 * d0));
            float wgt = expf(-d2 * inv2s2);
            w1 += wgt;
            const float* sp = seg + ((size_t)(n * 8) * 128 + h2) * 128 + w2;
#pragma unroll
            for (int k = 0; k < 8; ++k)
                num[k] = fmaf(sp[(size_t)k * 16384], wgt, num[k]);
        }
    }

    float val;
#pragma unroll
    for (int k = 0; k < 8; ++k) {
        val = num[k] * segc[k];
#pragma unroll
        for (int s = 32; s > 0; s >>= 1) val += __shfl_xor(val, s, 64);
        if (lane == 0) atomicAdd(&acc[64 + n * 8 + k], val);
        val = w1 * segc[k];
#pragma unroll
        for (int s = 32; s > 0; s >>= 1) val += __shfl_xor(val, s, 64);
        if (lane == 0) atomicAdd(&acc[96 + n * 8 + k], val);
    }
}

__global__ void finalize_k(const float* __restrict__ acc, float* __restrict__ out)
{
    int l = threadIdx.x;
    float v = 0.f;
    if (l < 32) v = acc[l] / acc[32 + l] + acc[64 + l] / acc[96 + l];
#pragma unroll
    for (int s = 32; s > 0; s >>= 1) v += __shfl_xor(v, s, 64);
    if (l == 0) out[0] = v * (1.0f / 64.0f);
}

extern "C" void kernel_launch(void* const* d_in, const int* in_sizes, int n_in,
                              void* d_out, int out_size, void* d_ws, size_t ws_size,
                              hipStream_t stream)
{
    const float* images = (const float*)d_in[0];
    const float* seg    = (const float*)d_in[1];
    const float* w1 = (const float*)d_in[2]; const float* b1 = (const float*)d_in[3];
    const float* w2 = (const float*)d_in[4]; const float* b2 = (const float*)d_in[5];
    const float* w3 = (const float*)d_in[6]; const float* b3 = (const float*)d_in[7];
    const float* w4 = (const float*)d_in[8]; const float* b4 = (const float*)d_in[9];
    float* out = (float*)d_out;
    char* ws = (char*)d_ws;
    float* P0 = (float*)(ws + OFF_P0);
    float* P1 = (float*)(ws + OFF_P1);
    float* P2 = (float*)(ws + OFF_P2);
    float* DS = (float*)(ws + OFF_DS);
    float* IT = (float*)(ws + OFF_IT);
    float* ST = (float*)(ws + OFF_ST);
    float* AC = (float*)(ws + OFF_AC);

    // VGG stem — grid = N * (Cout/8) * (H/16) * (W/32)
    conv3x3_v5<3><<<1024, 256, 0, stream>>>(images, w1, b1, P0, 4, 3, 64, 128, 128);
    conv3x3_v5<4><<<1024, 256, 0, stream>>>(P0, w2, b2, P1, 4, 64, 64, 128, 128);
    maxpool2_k<<<4096, 256, 0, stream>>>(P1, P2, 1048576);
    conv3x3_v5<4><<<512, 256, 0, stream>>>(P2, w3, b3, P0, 4, 64, 128, 64, 64);
    conv3x3_v5<4><<<512, 256, 0, stream>>>(P0, w4, b4, P1, 4, 128, 128, 64, 64);

    // batchnorm stats
    bn_stats_k<<<128, 256, 0, stream>>>(P1, ST, 128, 4096, 4);
    bn_stats_k<<<3, 256, 0, stream>>>(images, ST + 256, 3, 16384, 4);

    // normalize + transpose
    norm_transpose_f_k<<<2048, 256, 0, stream>>>(P1, ST, P0);
    norm_transpose_i_k<<<256, 256, 0, stream>>>(images, ST + 256, IT);

    // downsample segmentation 128 -> 64
    avgpool2_k<<<512, 256, 0, stream>>>(seg, DS, 131072);

    // modularity terms
    zero_k<<<1, 128, 0, stream>>>(AC);
    modularity64_v2<<<256, 64, 0, stream>>>(P0, DS, AC);
    modularity128_k<<<256, 256, 0, stream>>>(IT, seg, AC);

    finalize_k<<<1, 64, 0, stream>>>(AC, out);
}

// Round 7
// 747.367 us; speedup vs baseline: 1.2867x; 1.2867x over previous
//
#include <hip/hip_runtime.h>
#include <hip/hip_bf16.h>
#include <math.h>

// ---------------- workspace layout (bytes) ----------------
#define OFF_P0 0
#define OFF_P1 16777216
#define OFF_P2 33554432
#define OFF_DS 37748736
#define OFF_IT 38273024
#define OFF_ST 39059456
#define OFF_AC 39063552

// ---------------- conv 3x3 SAME + bias + relu (v6) ----------------
// v4 structure (16x16 px tile, 1 px x 8 oc per thread, max grid density) +
// (1) staging maps precomputed once (no div/mod in K-loop),
// (2) LDS row stride 40 -> bank = tx + 8*ty, exactly 2 lanes/bank = free.
// Weights via block-uniform s_load on the scalar pipe.
template<int CB>
__global__ __launch_bounds__(256) void conv3x3_v6(
    const float* __restrict__ in, const float* __restrict__ w,
    const float* __restrict__ b, float* __restrict__ out,
    int N, int Cin, int Cout, int H, int W)
{
    const int TW = W >> 4, TH = H >> 4, OCG = Cout >> 3;
    int bid = blockIdx.x;
    int txt = bid % TW; bid /= TW;
    int tyt = bid % TH; bid /= TH;
    int ocg = bid % OCG; bid /= OCG;
    int n = bid;
    int x0 = txt * 16, y0 = tyt * 16;
    int tid = threadIdx.x;
    int tx = tid & 15, ty = tid >> 4;

    __shared__ float lds[CB * 18 * 40];

    constexpr int NSLOT = CB * 324;
    constexpr int NT = (NSLOT + 255) / 256;

    // ---- precompute staging maps (K-invariant) ----
    int goff[NT], loff[NT];
    unsigned vmask = 0;
    const int HW = H * W;
#pragma unroll
    for (int t = 0; t < NT; ++t) {
        int i = tid + t * 256;
        int cc = i / 324;
        int rem = i - cc * 324;
        int r = rem / 18;
        int c = rem - r * 18;
        int y = y0 - 1 + r, x = x0 - 1 + c;
        goff[t] = cc * HW + y * W + x;
        loff[t] = cc * 720 + r * 40 + c;
        if (i < NSLOT && (unsigned)y < (unsigned)H && (unsigned)x < (unsigned)W)
            vmask |= (1u << t);
        else
            goff[t] = 0;             // safe address
        if (i >= NSLOT) loff[t] = -1;
    }

    float acc[8];
#pragma unroll
    for (int oc = 0; oc < 8; ++oc) acc[oc] = 0.f;

    const float* in_n = in + (size_t)n * Cin * HW;
    const float* w_g  = w + (size_t)(ocg * 8) * Cin * 9;

    for (int c0 = 0; c0 < Cin; c0 += CB) {
        const float* ip = in_n + (size_t)c0 * HW;
        __syncthreads();
#pragma unroll
        for (int t = 0; t < NT; ++t) {
            if (loff[t] >= 0) {
                float v = (vmask & (1u << t)) ? ip[goff[t]] : 0.f;
                lds[loff[t]] = v;
            }
        }
        __syncthreads();

#pragma unroll
        for (int cc = 0; cc < CB; ++cc) {
            const float* base = &lds[cc * 720 + ty * 40 + tx];
            float i00 = base[0];
            float i01 = base[1];
            float i02 = base[2];
            float i10 = base[40];
            float i11 = base[41];
            float i12 = base[42];
            float i20 = base[80];
            float i21 = base[81];
            float i22 = base[82];
            const float* wp = w_g + (size_t)(c0 + cc) * 9;
#pragma unroll
            for (int oc = 0; oc < 8; ++oc) {
                const float* wq = wp + (size_t)oc * Cin * 9;  // block-uniform -> s_load
                float a = acc[oc];
                a = fmaf(wq[0], i00, a);
                a = fmaf(wq[1], i01, a);
                a = fmaf(wq[2], i02, a);
                a = fmaf(wq[3], i10, a);
                a = fmaf(wq[4], i11, a);
                a = fmaf(wq[5], i12, a);
                a = fmaf(wq[6], i20, a);
                a = fmaf(wq[7], i21, a);
                a = fmaf(wq[8], i22, a);
                acc[oc] = a;
            }
        }
    }

#pragma unroll
    for (int oc = 0; oc < 8; ++oc) {
        float v = acc[oc] + b[ocg * 8 + oc];
        v = fmaxf(v, 0.f);
        out[((size_t)(n * Cout + ocg * 8 + oc) * H + (y0 + ty)) * W + (x0 + tx)] = v;
    }
}

// ---------------- 2x2 pools ----------------
__global__ __launch_bounds__(256) void maxpool2_k(const float* __restrict__ in,
                                                  float* __restrict__ out, int total)
{
    int tid = blockIdx.x * 256 + threadIdx.x;
    if (tid >= total) return;
    int wo = tid & 63, ho = (tid >> 6) & 63, ch = tid >> 12;
    const float* p = in + (size_t)ch * 16384 + (size_t)(ho * 2) * 128 + wo * 2;
    out[tid] = fmaxf(fmaxf(p[0], p[1]), fmaxf(p[128], p[129]));
}

__global__ __launch_bounds__(256) void avgpool2_k(const float* __restrict__ in,
                                                  float* __restrict__ out, int total)
{
    int tid = blockIdx.x * 256 + threadIdx.x;
    if (tid >= total) return;
    int wo = tid & 63, ho = (tid >> 6) & 63, ch = tid >> 12;
    const float* p = in + (size_t)ch * 16384 + (size_t)(ho * 2) * 128 + wo * 2;
    out[tid] = 0.25f * ((p[0] + p[1]) + (p[128] + p[129]));
}

// ---------------- batchnorm stats ----------------
__global__ __launch_bounds__(256) void bn_stats_k(const float* __restrict__ x,
                                                  float* __restrict__ stats,
                                                  int C, int HW, int N)
{
    int c = blockIdx.x, tid = threadIdx.x;
    int M = N * HW;
    double s = 0.0, s2 = 0.0;
    for (int i = tid; i < M; i += 256) {
        int n = i / HW, r = i - n * HW;
        float v = x[((size_t)(n * C + c)) * HW + r];
        s += v;
        s2 += (double)v * (double)v;
    }
    __shared__ double ls[256], ls2[256];
    ls[tid] = s; ls2[tid] = s2;
    __syncthreads();
    for (int st = 128; st > 0; st >>= 1) {
        if (tid < st) { ls[tid] += ls[tid + st]; ls2[tid] += ls2[tid + st]; }
        __syncthreads();
    }
    if (tid == 0) {
        double mean = ls[0] / M;
        double var = ls2[0] / M - mean * mean;
        stats[c] = (float)mean;
        stats[C + c] = (float)(1.0 / sqrt(var + 1e-5));
    }
}

// ---------------- normalize + transpose fich: (4,128,64,64)->(4,64,64,128) ---
__global__ __launch_bounds__(256) void norm_transpose_f_k(
    const float* __restrict__ x, const float* __restrict__ stats,
    float* __restrict__ xt)
{
    int bid = blockIdx.x;           // n(4) x h(64) x ct(4) x wt(2)
    int wt = bid & 1; bid >>= 1;
    int ct = bid & 3; bid >>= 2;
    int h = bid & 63; bid >>= 6;
    int n = bid;
    int tx = threadIdx.x & 31, ty = threadIdx.x >> 5;
    __shared__ float lds[32][33];
    int c0 = ct * 32, w0 = wt * 32;
#pragma unroll
    for (int i = 0; i < 4; ++i) {
        int c = c0 + ty + i * 8;
        float v = x[(((size_t)n * 128 + c) * 64 + h) * 64 + (w0 + tx)];
        lds[ty + i * 8][tx] = (v - stats[c]) * stats[128 + c];
    }
    __syncthreads();
#pragma unroll
    for (int i = 0; i < 4; ++i) {
        int wcol = w0 + ty + i * 8;
        xt[(((size_t)(n * 64) + h) * 64 + wcol) * 128 + c0 + tx] = lds[tx][ty + i * 8];
    }
}

// ---------------- normalize + transpose images ----------------
__global__ __launch_bounds__(256) void norm_transpose_i_k(
    const float* __restrict__ x, const float* __restrict__ stats,
    float* __restrict__ it)
{
    int tid = blockIdx.x * 256 + threadIdx.x;   // 65536
    int n = tid >> 14;
    int hw = tid & 16383;
#pragma unroll
    for (int c = 0; c < 3; ++c) {
        float v = x[(((size_t)n * 3 + c) << 14) + hw];
        it[(size_t)tid * 3 + c] = (v - stats[c]) * stats[3 + c];
    }
}

__global__ void zero_k(float* acc)
{
    if (threadIdx.x < 128) acc[threadIdx.x] = 0.f;
}

// ---------------- modularity on VGG features (v2) ----------------
__global__ __launch_bounds__(64) void modularity64_v2(
    const float* __restrict__ xt,   // (4,64,64,128)
    const float* __restrict__ seg,  // (4,8,64,64)
    float* __restrict__ acc)        // [0..31] num, [32..63] den
{
    __shared__ float fl[12][12][20];
    __shared__ float sl[8][12][14];

    int t = threadIdx.x;
    int tx = t & 7, ty = t >> 3;
    int bid = blockIdx.x;              // n(4) x by(8) x bx(8)
    int bx = bid & 7; bid >>= 3;
    int by = bid & 7; bid >>= 3;
    int n = bid;
    int x0 = bx * 8, y0 = by * 8;

    for (int i = t; i < 8 * 144; i += 64) {
        int k = i / 144;
        int rem = i - k * 144;
        int r = rem / 12, c = rem - r * 12;
        int y = y0 - 2 + r, x = x0 - 2 + c;
        float v = 0.f;
        if ((unsigned)y < 64u && (unsigned)x < 64u)
            v = seg[((size_t)(n * 8 + k) * 64 + y) * 64 + x];
        sl[k][r][c] = v;
    }

    float d2p[25];
#pragma unroll
    for (int di = 0; di < 5; ++di)
#pragma unroll
        for (int dj = 0; dj < 5; ++dj) {
            int y2 = y0 + ty + di - 2, x2 = x0 + tx + dj - 2;
            d2p[di * 5 + dj] = ((unsigned)y2 < 64u && (unsigned)x2 < 64u) ? 0.f : 1e30f;
        }

    for (int ch0 = 0; ch0 < 128; ch0 += 16) {
        __syncthreads();
        for (int i = t; i < 576; i += 64) {
            int pix = i >> 2, q = i & 3;
            int r = pix / 12, c = pix - r * 12;
            int y = y0 - 2 + r, x = x0 - 2 + c;
            float4 v = make_float4(0.f, 0.f, 0.f, 0.f);
            if ((unsigned)y < 64u && (unsigned)x < 64u)
                v = *(const float4*)&xt[((size_t)((n * 64 + y) * 64 + x)) * 128 + ch0 + q * 4];
            *(float4*)&fl[r][c][q * 4] = v;
        }
        __syncthreads();

        float4 c0 = *(const float4*)&fl[ty + 2][tx + 2][0];
        float4 c1 = *(const float4*)&fl[ty + 2][tx + 2][4];
        float4 c2 = *(const float4*)&fl[ty + 2][tx + 2][8];
        float4 c3 = *(const float4*)&fl[ty + 2][tx + 2][12];
#pragma unroll
        for (int di = 0; di < 5; ++di)
#pragma unroll
            for (int dj = 0; dj < 5; ++dj) {
                const float* np = &fl[ty + di][tx + dj][0];
                float4 v0 = *(const float4*)(np + 0);
                float4 v1 = *(const float4*)(np + 4);
                float4 v2 = *(const float4*)(np + 8);
                float4 v3 = *(const float4*)(np + 12);
                float d = d2p[di * 5 + dj];
                float e;
                e = c0.x - v0.x; d = fmaf(e, e, d);
                e = c0.y - v0.y; d = fmaf(e, e, d);
                e = c0.z - v0.z; d = fmaf(e, e, d);
                e = c0.w - v0.w; d = fmaf(e, e, d);
                e = c1.x - v1.x; d = fmaf(e, e, d);
                e = c1.y - v1.y; d = fmaf(e, e, d);
                e = c1.z - v1.z; d = fmaf(e, e, d);
                e = c1.w - v1.w; d = fmaf(e, e, d);
                e = c2.x - v2.x; d = fmaf(e, e, d);
                e = c2.y - v2.y; d = fmaf(e, e, d);
                e = c2.z - v2.z; d = fmaf(e, e, d);
                e = c2.w - v2.w; d = fmaf(e, e, d);
                e = c3.x - v3.x; d = fmaf(e, e, d);
                e = c3.y - v3.y; d = fmaf(e, e, d);
                e = c3.z - v3.z; d = fmaf(e, e, d);
                e = c3.w - v3.w; d = fmaf(e, e, d);
                d2p[di * 5 + dj] = d;
            }
    }

    const float minus_inv2s2 = -1.0f / (2.0f * 0.02f * 0.02f); // -1250
    float wgt[25];
    float w1 = 0.f;
#pragma unroll
    for (int j = 0; j < 25; ++j) {
        wgt[j] = expf(d2p[j] * minus_inv2s2);
        w1 += wgt[j];
    }

#pragma unroll
    for (int k = 0; k < 8; ++k) {
        float s = 0.f;
#pragma unroll
        for (int di = 0; di < 5; ++di)
#pragma unroll
            for (int dj = 0; dj < 5; ++dj)
                s = fmaf(wgt[di * 5 + dj], sl[k][ty + di][tx + dj], s);
        float sc = sl[k][ty + 2][tx + 2];
        float numk = s * sc;
        float denk = w1 * sc;
#pragma unroll
        for (int sft = 32; sft > 0; sft >>= 1) {
            numk += __shfl_xor(numk, sft, 64);
            denk += __shfl_xor(denk, sft, 64);
        }
        if (t == 0) {
            atomicAdd(&acc[n * 8 + k], numk);
            atomicAdd(&acc[32 + n * 8 + k], denk);
        }
    }
}

// ---------------- modularity on images ----------------
__global__ __launch_bounds__(256) void modularity128_k(
    const float* __restrict__ it,   // (4,128,128,3)
    const float* __restrict__ seg,  // (4,8,128,128)
    float* __restrict__ acc)
{
    const float inv2s2 = 1.0f / (2.0f * 0.2f * 0.2f);
    int tid = blockIdx.x * 256 + threadIdx.x;
    int lane = threadIdx.x & 63;
    int w = tid & 127;
    int h = (tid >> 7) & 127;
    int n = tid >> 14;

    const float* cp = it + (size_t)tid * 3;
    float c0 = cp[0], c1 = cp[1], c2 = cp[2];
    float segc[8], num[8];
#pragma unroll
    for (int k = 0; k < 8; ++k) {
        segc[k] = seg[((size_t)(n * 8 + k) * 128 + h) * 128 + w];
        num[k] = 0.f;
    }
    float w1 = 0.f;

    for (int di = -2; di <= 2; ++di) {
        int h2 = h + di;
        if (h2 < 0 || h2 >= 128) continue;
        for (int dj = -2; dj <= 2; ++dj) {
            int w2 = w + dj;
            if (w2 < 0 || w2 >= 128) continue;
            const float* vp = it + ((size_t)((n * 128 + h2) * 128 + w2)) * 3;
            float d0 = c0 - vp[0], d1 = c1 - vp[1], d2v = c2 - vp[2];
            float d2 = fmaf(d2v, d2v, fmaf(d1, d1, d0 * d0));
            float wgt = expf(-d2 * inv2s2);
            w1 += wgt;
            const float* sp = seg + ((size_t)(n * 8) * 128 + h2) * 128 + w2;
#pragma unroll
            for (int k = 0; k < 8; ++k)
                num[k] = fmaf(sp[(size_t)k * 16384], wgt, num[k]);
        }
    }

    float val;
#pragma unroll
    for (int k = 0; k < 8; ++k) {
        val = num[k] * segc[k];
#pragma unroll
        for (int s = 32; s > 0; s >>= 1) val += __shfl_xor(val, s, 64);
        if (lane == 0) atomicAdd(&acc[64 + n * 8 + k], val);
        val = w1 * segc[k];
#pragma unroll
        for (int s = 32; s > 0; s >>= 1) val += __shfl_xor(val, s, 64);
        if (lane == 0) atomicAdd(&acc[96 + n * 8 + k], val);
    }
}

__global__ void finalize_k(const float* __restrict__ acc, float* __restrict__ out)
{
    int l = threadIdx.x;
    float v = 0.f;
    if (l < 32) v = acc[l] / acc[32 + l] + acc[64 + l] / acc[96 + l];
#pragma unroll
    for (int s = 32; s > 0; s >>= 1) v += __shfl_xor(v, s, 64);
    if (l == 0) out[0] = v * (1.0f / 64.0f);
}

extern "C" void kernel_launch(void* const* d_in, const int* in_sizes, int n_in,
                              void* d_out, int out_size, void* d_ws, size_t ws_size,
                              hipStream_t stream)
{
    const float* images = (const float*)d_in[0];
    const float* seg    = (const float*)d_in[1];
    const float* w1 = (const float*)d_in[2]; const float* b1 = (const float*)d_in[3];
    const float* w2 = (const float*)d_in[4]; const float* b2 = (const float*)d_in[5];
    const float* w3 = (const float*)d_in[6]; const float* b3 = (const float*)d_in[7];
    const float* w4 = (const float*)d_in[8]; const float* b4 = (const float*)d_in[9];
    float* out = (float*)d_out;
    char* ws = (char*)d_ws;
    float* P0 = (float*)(ws + OFF_P0);
    float* P1 = (float*)(ws + OFF_P1);
    float* P2 = (float*)(ws + OFF_P2);
    float* DS = (float*)(ws + OFF_DS);
    float* IT = (float*)(ws + OFF_IT);
    float* ST = (float*)(ws + OFF_ST);
    float* AC = (float*)(ws + OFF_AC);

    // VGG stem — grid = N * (Cout/8) * (H/16) * (W/16)
    conv3x3_v6<3><<<2048, 256, 0, stream>>>(images, w1, b1, P0, 4, 3, 64, 128, 128);
    conv3x3_v6<4><<<2048, 256, 0, stream>>>(P0, w2, b2, P1, 4, 64, 64, 128, 128);
    maxpool2_k<<<4096, 256, 0, stream>>>(P1, P2, 1048576);
    conv3x3_v6<4><<<1024, 256, 0, stream>>>(P2, w3, b3, P0, 4, 64, 128, 64, 64);
    conv3x3_v6<4><<<1024, 256, 0, stream>>>(P0, w4, b4, P1, 4, 128, 128, 64, 64);

    // batchnorm stats
    bn_stats_k<<<128, 256, 0, stream>>>(P1, ST, 128, 4096, 4);
    bn_stats_k<<<3, 256, 0, stream>>>(images, ST + 256, 3, 16384, 4);

    // normalize + transpose
    norm_transpose_f_k<<<2048, 256, 0, stream>>>(P1, ST, P0);
    norm_transpose_i_k<<<256, 256, 0, stream>>>(images, ST + 256, IT);

    // downsample segmentation 128 -> 64
    avgpool2_k<<<512, 256, 0, stream>>>(seg, DS, 131072);

    // modularity terms
    zero_k<<<1, 128, 0, stream>>>(AC);
    modularity64_v2<<<256, 64, 0, stream>>>(P0, DS, AC);
    modularity128_k<<<256, 256, 0, stream>>>(IT, seg, AC);

    finalize_k<<<1, 64, 0, stream>>>(AC, out);
}